// Round 10
// baseline (174.885 us; speedup 1.0000x reference)
//
#include <hip/hip_runtime.h>
#include <hip/hip_fp16.h>
#include <stdint.h>

#define NROWS 8192   // B*S
#define HDIM  128
#define KSUB  8
#define NC    4096
#define DSUB  16
#define OUTD  6

#define FB_TAU 3e-4f                // fallback margin; split-fp16 distance error bound ~4e-5
#define DOTSCALE (-2.0f / 4096.0f)  // undo x*256, c*16 scaling; exact pow2

typedef _Float16 f16x8 __attribute__((ext_vector_type(8)));
typedef float    f32x16 __attribute__((ext_vector_type(16)));

// ws layout (bytes): total ~7.4 MiB
#define XK_OFF 0u            // xk:   [KSUB][NROWS][DSUB] fp32, 4 MiB
#define CN_OFF 4194304u      // cnorm:[KSUB][NC] fp32, 128 KiB
#define B2_OFF 4325376u      // B2S:  [KSUB][128 units][2 halves][64 lanes] f16x8, 2 MiB
#define PK_OFF 6422528u      // pk:   [2 splits][NROWS][KSUB] u64, 1 MiB

// ---------------- Kernel 1: prep = MLP + cnorm + bprep (256 blocks) ----------------
__global__ __launch_bounds__(256) void prep_kernel(
    const float* __restrict__ z, const float* __restrict__ W1, const float* __restrict__ b1,
    const float* __restrict__ W2, const float* __restrict__ b2,
    const float* __restrict__ ce,
    float* __restrict__ xk, float* __restrict__ cnorm, f16x8* __restrict__ B2S)
{
    __shared__ float h1s[32 * HDIM];    // 16 KiB
    __shared__ float w2s[HDIM * HDIM];  // 64 KiB
    const int t = threadIdx.x;
    const int row0 = blockIdx.x * 32;

    // ---- bprep for 32x32x16 MFMA: entry e = (k, unit, half, lane) ----
    // B[kd][n]: n = unit*32 + (lane&31), kd = (lane>>5)*8 + j; half 0=hi, 1=lo.
    #pragma unroll
    for (int q = 0; q < 2; ++q) {
        const int e = blockIdx.x * 512 + q * 256 + t;    // 0..131071
        const int k    = e >> 14;
        const int unit = (e >> 7) & 127;
        const int half = (e >> 6) & 1;
        const int lane = e & 63;
        const int n    = unit * 32 + (lane & 31);
        const int dims = (lane >> 5) * 8;
        const float* cp = &ce[((size_t)k * NC + n) * DSUB + dims];
        f16x8 hi, lo;
        #pragma unroll
        for (int j = 0; j < 8; ++j) {
            const float s = cp[j] * 16.0f;               // pow2 scale keeps lo normal
            const _Float16 h = (_Float16)s;
            hi[j] = h;
            lo[j] = (_Float16)(s - (float)h);
        }
        B2S[e] = half ? lo : hi;
    }

    // centroid norms (first 128 blocks cover KSUB*NC = 32768 centroids)
    if (blockIdx.x < (KSUB * NC) / 256) {
        const int g = blockIdx.x * 256 + t;
        const float4* cp = (const float4*)&ce[(size_t)g * DSUB];
        float nn = 0.f;
        #pragma unroll
        for (int q = 0; q < 4; ++q) {
            const float4 v = cp[q];
            nn = fmaf(v.x, v.x, nn); nn = fmaf(v.y, v.y, nn);
            nn = fmaf(v.z, v.z, nn); nn = fmaf(v.w, v.w, nn);
        }
        cnorm[g] = nn;
    }

    // stage W2 (coalesced)
    {
        const float4* g4 = (const float4*)W2;
        float4* s4 = (float4*)w2s;
        #pragma unroll
        for (int q = 0; q < 16; ++q) s4[t + q * 256] = g4[t + q * 256];
    }

    // phase A: h1 = relu(z @ W1 + b1) into LDS (32x128)
    #pragma unroll
    for (int e = 0; e < 16; ++e) {
        const int idx = e * 256 + t;
        const int r = idx >> 7, j = idx & 127;
        const int n = row0 + r;
        float acc = b1[j];
        acc = fmaf(z[n * 3 + 0], W1[0 * HDIM + j], acc);
        acc = fmaf(z[n * 3 + 1], W1[1 * HDIM + j], acc);
        acc = fmaf(z[n * 3 + 2], W1[2 * HDIM + j], acc);
        h1s[idx] = fmaxf(acc, 0.f);
    }
    __syncthreads();

    // phase B: 4 rows x 4 cols per thread
    const int c4 = (t & 31) * 4;
    const int r4 = (t >> 5) * 4;
    float acc[4][4];
    #pragma unroll
    for (int a = 0; a < 4; ++a)
        #pragma unroll
        for (int b = 0; b < 4; ++b) acc[a][b] = 0.f;

    for (int k4 = 0; k4 < HDIM; k4 += 4) {
        float hh[4][4], ww[4][4];
        #pragma unroll
        for (int q = 0; q < 4; ++q) {
            const float4 v = *(const float4*)&h1s[(r4 + q) * HDIM + k4];
            hh[q][0] = v.x; hh[q][1] = v.y; hh[q][2] = v.z; hh[q][3] = v.w;
        }
        #pragma unroll
        for (int p = 0; p < 4; ++p) {
            const float4 v = *(const float4*)&w2s[(k4 + p) * HDIM + c4];
            ww[p][0] = v.x; ww[p][1] = v.y; ww[p][2] = v.z; ww[p][3] = v.w;
        }
        #pragma unroll
        for (int q = 0; q < 4; ++q)
            #pragma unroll
            for (int p = 0; p < 4; ++p) {
                acc[q][0] = fmaf(hh[q][p], ww[p][0], acc[q][0]);
                acc[q][1] = fmaf(hh[q][p], ww[p][1], acc[q][1]);
                acc[q][2] = fmaf(hh[q][p], ww[p][2], acc[q][2]);
                acc[q][3] = fmaf(hh[q][p], ww[p][3], acc[q][3]);
            }
    }

    const float4 bb = *(const float4*)&b2[c4];
    const int kk = c4 >> 4;
    const int dd = c4 & 15;
    #pragma unroll
    for (int q = 0; q < 4; ++q) {
        float4 o;
        o.x = fmaxf(acc[q][0] + bb.x, 0.f);
        o.y = fmaxf(acc[q][1] + bb.y, 0.f);
        o.z = fmaxf(acc[q][2] + bb.z, 0.f);
        o.w = fmaxf(acc[q][3] + bb.w, 0.f);
        *(float4*)&xk[((size_t)kk * NROWS + (row0 + r4 + q)) * DSUB + dd] = o;
    }
}

// ---------------- Kernel 2: MFMA 32x32 argmin ----------------
// grid (64 rowblocks, 8 k, 2 cz) = 1024 blocks = exactly 4/CU. Block = 4 waves
// x 32 rows each; 2048 centroids (64 units of 32 cols) staged in 16-unit LDS
// chunks shared by all 4 waves. One 4-chained 32x32x16 MFMA group = 1024 exact
// split-fp16 dots per 2 LDS b128 reads (2x less LDS + MFMA issue/dot vs 16x16).
__global__ __launch_bounds__(256, 4) void argmin_kernel(
    const float* __restrict__ xk, const f16x8* __restrict__ B2S,
    const float* __restrict__ cnorm, unsigned long long* __restrict__ pk)
{
    __shared__ f16x8 cs[16 * 2 * 64];   // 32 KiB = 16 units
    __shared__ float cnS[2048];         // 8 KiB norms for this split
    const int t = threadIdx.x;
    const int lane = t & 63;
    const int wid  = t >> 6;
    const int k  = blockIdx.y;                 // 0..7
    const int cz = blockIdx.z;                 // 0..1
    const int rowbase = blockIdx.x * 128 + wid * 32;
    const int col = lane & 31;
    const int khl = lane >> 5;                 // which K-half this lane holds

    // stage the 2048 norms of this split (once)
    {
        const float* cnp0 = &cnorm[k * NC + cz * 2048];
        #pragma unroll
        for (int q = 0; q < 8; ++q) cnS[t + q * 256] = cnp0[t + q * 256];
    }

    // A fragments: 32 rows, A[m=lane&31][kd=(lane>>5)*8+j], hi/lo split (exact)
    f16x8 Ah, Al;
    {
        const float* xp = &xk[((size_t)k * NROWS + rowbase + col) * DSUB + khl * 8];
        #pragma unroll
        for (int j = 0; j < 8; ++j) {
            const float s = xp[j] * 256.0f;
            const _Float16 h = (_Float16)s;
            Ah[j] = h;
            Al[j] = (_Float16)(s - (float)h);
        }
    }

    float m1[16], m2[16];
    int   idx[16];
    #pragma unroll
    for (int r = 0; r < 16; ++r) { m1[r] = 1e30f; m2[r] = 1e30f; idx[r] = 0; }

    const f16x8* gB = &B2S[((size_t)(k * 128 + cz * 64)) * 128];  // unit = 128 f16x8
    const f32x16 zero16 = {0.f,0.f,0.f,0.f,0.f,0.f,0.f,0.f,
                           0.f,0.f,0.f,0.f,0.f,0.f,0.f,0.f};

    for (int ch = 0; ch < 4; ++ch) {
        __syncthreads();                       // previous chunk consumed
        {   // stage 16 units (32 KiB): 2048 uint4, 8 per thread, coalesced
            const uint4* g4 = (const uint4*)gB + ch * 2048;
            uint4* s4 = (uint4*)cs;
            #pragma unroll
            for (int q = 0; q < 8; ++q) s4[t + q * 256] = g4[t + q * 256];
        }
        __syncthreads();

        #pragma unroll 2
        for (int u = 0; u < 16; ++u) {
            const f16x8 Bh = cs[u * 128 + lane];
            const f16x8 Bl = cs[u * 128 + 64 + lane];
            const float nrm = cnS[(ch * 16 + u) * 32 + col];
            f32x16 acc = __builtin_amdgcn_mfma_f32_32x32x16_f16(Ah, Bh, zero16, 0, 0, 0);
            acc = __builtin_amdgcn_mfma_f32_32x32x16_f16(Al, Bl, acc, 0, 0, 0);
            acc = __builtin_amdgcn_mfma_f32_32x32x16_f16(Ah, Bl, acc, 0, 0, 0);
            acc = __builtin_amdgcn_mfma_f32_32x32x16_f16(Al, Bh, acc, 0, 0, 0);
            const int c = cz * 2048 + (ch * 16 + u) * 32 + col;
            #pragma unroll
            for (int r = 0; r < 16; ++r) {
                const float s = fmaf(acc[r], DOTSCALE, nrm);   // = nrm - 2*dot
                const bool lt = s < m1[r];
                m2[r] = __builtin_amdgcn_fmed3f(s, m1[r], m2[r]);
                idx[r] = lt ? c : idx[r];
                m1[r] = fminf(s, m1[r]);
            }
        }
    }

    // reduce across the 32 col-lanes holding each row (xor 1,2,4,8,16)
    #pragma unroll
    for (int off = 1; off < 32; off <<= 1) {
        #pragma unroll
        for (int r = 0; r < 16; ++r) {
            const float om1 = __shfl_xor(m1[r], off, 64);
            const float om2 = __shfl_xor(m2[r], off, 64);
            const int  oidx = __shfl_xor(idx[r], off, 64);
            const bool better = (om1 < m1[r]) ||
                                (om1 == m1[r] && oidx < idx[r]);
            m2[r] = fminf(fminf(m2[r], om2), fmaxf(m1[r], om1));
            m1[r] = better ? om1 : m1[r];
            idx[r] = better ? oidx : idx[r];
        }
    }

    if (col == 0) {   // lanes 0 and 32 hold final results for their 16 rows
        #pragma unroll
        for (int r = 0; r < 16; ++r) {
            const int row = rowbase + (r & 3) + 8 * (r >> 2) + 4 * khl;
            unsigned u = __float_as_uint(m1[r]);
            u = (u & 0x80000000u) ? ~u : (u | 0x80000000u);      // order-preserving
            const unsigned short dh =
                __half_as_ushort(__float2half(m2[r] - m1[r]));
            pk[((size_t)cz * NROWS + row) * KSUB + k] =
                ((unsigned long long)u << 32) |
                ((unsigned)dh << 16) | (unsigned)idx[r];
        }
    }
}

// ---------------- Kernel 3: finish = merge + exact rescue + LUT output ----------------
__global__ __launch_bounds__(256) void finish_kernel(
    const float* __restrict__ xk, const float* __restrict__ ce,
    const float* __restrict__ cnorm, const unsigned long long* __restrict__ pk,
    const float* __restrict__ W3, const float* __restrict__ b3,
    float* __restrict__ out)
{
    __shared__ int codes_s[256];
    __shared__ int wl_s[256];
    __shared__ int wcnt;
    const int t = threadIdx.x;
    const int row0 = blockIdx.x * 32;
    if (t == 0) wcnt = 0;
    __syncthreads();

    // merge 2 splits for (row, k) = (row0 + t>>3, t&7)
    {
        const int row = row0 + (t >> 3);
        const int k = t & 7;
        const unsigned long long a = pk[(size_t)row * KSUB + k];
        const unsigned long long b = pk[((size_t)NROWS + row) * KSUB + k];
        const unsigned long long w = a < b ? a : b;
        const unsigned long long l = a < b ? b : a;
        const unsigned uw = (unsigned)(w >> 32), ul = (unsigned)(l >> 32);
        const float m1w = __uint_as_float((uw & 0x80000000u) ? (uw ^ 0x80000000u) : ~uw);
        const float m1l = __uint_as_float((ul & 0x80000000u) ? (ul ^ 0x80000000u) : ~ul);
        const float m2g = fminf(
            m1w + (float)__ushort_as_half((unsigned short)((unsigned)w >> 16)), m1l);
        codes_s[t] = (int)(w & 0xFFFFull);
        if (m2g - m1w < FB_TAU) {      // near-tie: exact fp32 rescan needed
            const int slot = atomicAdd(&wcnt, 1);
            wl_s[slot] = t;
        }
    }
    __syncthreads();

    // exact fp32 rescue, wave-per-item over the block-local worklist
    {
        const int lane = t & 63;
        const int wid = t >> 6;
        const int nitems = wcnt;
        for (int i = wid; i < nitems; i += 4) {
            const int wg = wl_s[i];
            const int row = row0 + (wg >> 3), k = wg & 7;
            float xr[DSUB];
            {
                const float* xp = &xk[((size_t)k * NROWS + row) * DSUB];
                #pragma unroll
                for (int q = 0; q < DSUB; q += 4) {
                    const float4 v = *(const float4*)&xp[q];
                    xr[q + 0] = -2.f * v.x; xr[q + 1] = -2.f * v.y;
                    xr[q + 2] = -2.f * v.z; xr[q + 3] = -2.f * v.w;
                }
            }
            float bm = 1e30f; int bi = NC;
            for (int c = lane; c < NC; c += 64) {
                const float* cp = &ce[((size_t)k * NC + c) * DSUB];
                float s = cnorm[k * NC + c];
                #pragma unroll
                for (int d = 0; d < DSUB; ++d) s = fmaf(xr[d], cp[d], s);
                if (s < bm) { bm = s; bi = c; }
            }
            #pragma unroll
            for (int off = 1; off < 64; off <<= 1) {
                const float om = __shfl_xor(bm, off, 64);
                const int  oi = __shfl_xor(bi, off, 64);
                const bool better = (om < bm) || (om == bm && oi < bi);
                bm = better ? om : bm;
                bi = better ? oi : bi;
            }
            if (lane == 0) codes_s[wg] = bi;
        }
    }
    __syncthreads();

    // output: 32 rows x 6 = 192 outputs
    if (t < 32 * OUTD) {
        const int nl = t / OUTD;
        const int o = t - nl * OUTD;
        const int n = row0 + nl;
        float acc = b3[o];
        #pragma unroll
        for (int k = 0; k < KSUB; ++k) {
            const int code = codes_s[nl * KSUB + k];
            const float* cp = &ce[((size_t)k * NC + code) * DSUB];
            const float* wp = &W3[(k * DSUB) * OUTD + o];
            #pragma unroll
            for (int d = 0; d < DSUB; ++d)
                acc = fmaf(cp[d], wp[d * OUTD], acc);
        }
        out[n * OUTD + o] = acc;
    }
}

extern "C" void kernel_launch(void* const* d_in, const int* in_sizes, int n_in,
                              void* d_out, int out_size, void* d_ws, size_t ws_size,
                              hipStream_t stream)
{
    const float* z  = (const float*)d_in[0];
    const float* W1 = (const float*)d_in[1];
    const float* b1 = (const float*)d_in[2];
    const float* W2 = (const float*)d_in[3];
    const float* b2 = (const float*)d_in[4];
    const float* ce = (const float*)d_in[5];
    const float* W3 = (const float*)d_in[6];
    const float* b3 = (const float*)d_in[7];

    char* ws = (char*)d_ws;
    float* xk    = (float*)(ws + XK_OFF);
    float* cnorm = (float*)(ws + CN_OFF);
    f16x8* B2S   = (f16x8*)(ws + B2_OFF);
    unsigned long long* pk = (unsigned long long*)(ws + PK_OFF);

    hipLaunchKernelGGL(prep_kernel, dim3(256), dim3(256), 0, stream,
                       z, W1, b1, W2, b2, ce, xk, cnorm, B2S);
    hipLaunchKernelGGL(argmin_kernel, dim3(64, 8, 2), dim3(256), 0, stream,
                       xk, B2S, cnorm, pk);
    hipLaunchKernelGGL(finish_kernel, dim3(256), dim3(256), 0, stream,
                       xk, ce, cnorm, pk, W3, b3, (float*)d_out);
}